// Round 4
// baseline (321.834 us; speedup 1.0000x reference)
//
#include <hip/hip_runtime.h>
#include <math.h>

#define NN 4096
#define DD 512
#define FF 512
#define CAP 256
#define SCALE 0.08838834764831845f

typedef __attribute__((ext_vector_type(8))) short short8;
typedef __attribute__((ext_vector_type(8))) unsigned short ushort8;
typedef __attribute__((ext_vector_type(4))) float floatx4;

__device__ __forceinline__ float bf2f(unsigned short u) {
    union { unsigned int i; float f; } x; x.i = ((unsigned int)u) << 16; return x.f;
}
__device__ __forceinline__ unsigned short f2bf(float f) {
    union { float f; unsigned int i; } x; x.f = f;
    unsigned int r = (x.i + 0x7FFFu + ((x.i >> 16) & 1u)) >> 16;
    return (unsigned short)r;
}
__device__ __forceinline__ void gld_lds16(const void* g, void* l) {
    __builtin_amdgcn_global_load_lds((const __attribute__((address_space(1))) void*)g,
                                     (__attribute__((address_space(3))) void*)l, 16, 0, 0);
}

// ---------------------------------------------------------------- mask -> idx
__global__ void build_idx_kernel(const int* __restrict__ mask,
                                 int* __restrict__ idx, int* __restrict__ cnt) {
    int row = blockIdx.x;
    __shared__ int c;
    if (threadIdx.x == 0) c = 0;
    __syncthreads();
    const int4* mrow = (const int4*)(mask + (size_t)row * NN);
    for (int j4 = threadIdx.x; j4 < NN / 4; j4 += blockDim.x) {
        int4 m4 = mrow[j4];
        int base = j4 * 4;
        if (m4.x == 0) idx[row * CAP + atomicAdd(&c, 1)] = base;
        if (m4.y == 0) idx[row * CAP + atomicAdd(&c, 1)] = base + 1;
        if (m4.z == 0) idx[row * CAP + atomicAdd(&c, 1)] = base + 2;
        if (m4.w == 0) idx[row * CAP + atomicAdd(&c, 1)] = base + 3;
    }
    __syncthreads();
    if (threadIdx.x == 0) cnt[row] = (c < CAP) ? c : CAP;
}

// ---------------------------------------------------------------- weight fold
// region r = l*6 + m, m: 0=q 1=k 2=v 3=o 4=fc1 5=fc2
// folded (m<3: ln1; m==4: ln2): wc = W*g (bf16), c1 = sum(W*g), c0 = sum(b_ln*W)+bias
// plain  (m==3, m==5):          wc = W (bf16),   c1 = 0,        c0 = bias
struct FoldArgs {
    const float* w[6];
    const float* bias[6];
    const float* ln1_g; const float* ln1_b;
    const float* ln2_g; const float* ln2_b;
};
__global__ void fold_weights(FoldArgs fa, unsigned short* __restrict__ wc,
                             float* __restrict__ c0, float* __restrict__ c1) {
    int r = blockIdx.y;
    int l = r / 6, m = r - l * 6;
    int wave = threadIdx.x >> 6, lane = threadIdx.x & 63;
    int n = blockIdx.x * 4 + wave;

    const float* wrow = fa.w[m] + (size_t)l * DD * DD + (size_t)n * DD;
    float4 w0 = *(const float4*)&wrow[lane * 8];
    float4 w1 = *(const float4*)&wrow[lane * 8 + 4];
    float we[8] = {w0.x, w0.y, w0.z, w0.w, w1.x, w1.y, w1.z, w1.w};

    bool folded = (m < 3) || (m == 4);
    float s1 = 0.f, sb = 0.f;
    float wg[8];
    if (folded) {
        const float* gp = (m < 3) ? fa.ln1_g + l * DD : fa.ln2_g + l * DD;
        const float* bp = (m < 3) ? fa.ln1_b + l * DD : fa.ln2_b + l * DD;
        float4 g0 = *(const float4*)&gp[lane * 8];
        float4 g1 = *(const float4*)&gp[lane * 8 + 4];
        float4 b0 = *(const float4*)&bp[lane * 8];
        float4 b1 = *(const float4*)&bp[lane * 8 + 4];
        float ge[8] = {g0.x, g0.y, g0.z, g0.w, g1.x, g1.y, g1.z, g1.w};
        float be[8] = {b0.x, b0.y, b0.z, b0.w, b1.x, b1.y, b1.z, b1.w};
#pragma unroll
        for (int e = 0; e < 8; e++) {
            wg[e] = we[e] * ge[e];
            s1 += wg[e];
            sb += we[e] * be[e];
        }
    } else {
#pragma unroll
        for (int e = 0; e < 8; e++) wg[e] = we[e];
    }
    ushort8 ov;
#pragma unroll
    for (int e = 0; e < 8; e++) ov[e] = f2bf(wg[e]);
    *(ushort8*)&wc[(size_t)r * DD * DD + (size_t)n * DD + lane * 8] = ov;

    if (folded) {
#pragma unroll
        for (int off = 32; off; off >>= 1) { s1 += __shfl_xor(s1, off); sb += __shfl_xor(sb, off); }
    }
    if (lane == 0) {
        c1[r * DD + n] = folded ? s1 : 0.f;
        c0[r * DD + n] = (folded ? sb : 0.f) + fa.bias[m][l * DD + n];
    }
}

// ---------------------------------------------------------------- init: bf16(x) + row stats
__global__ void init_stats(const float* __restrict__ x, unsigned short* __restrict__ xb,
                           float* __restrict__ S) {
    int wave = threadIdx.x >> 6, lane = threadIdx.x & 63;
    int row = blockIdx.x * 4 + wave;
    const float* xr = x + (size_t)row * DD;
    float4 p0 = *(const float4*)&xr[lane * 8];
    float4 p1 = *(const float4*)&xr[lane * 8 + 4];
    float v[8] = {p0.x, p0.y, p0.z, p0.w, p1.x, p1.y, p1.z, p1.w};
    float s = 0.f, q = 0.f;
    ushort8 ov;
#pragma unroll
    for (int e = 0; e < 8; e++) { s += v[e]; q += v[e] * v[e]; ov[e] = f2bf(v[e]); }
#pragma unroll
    for (int off = 32; off; off >>= 1) { s += __shfl_xor(s, off); q += __shfl_xor(q, off); }
    *(ushort8*)&xb[(size_t)row * DD + lane * 8] = ov;
    if (lane == 0) { S[2 * row] = s; S[2 * row + 1] = q; }
}

__global__ void zero_kernel(float* __restrict__ p, int n) {
    int i = blockIdx.x * blockDim.x + threadIdx.x;
    if (i < n) p[i] = 0.f;
}

// ---------------------------------------------------------------- bf16 MFMA GEMM, 64x64 tile
// MODE 0: LN-folded -> bf16 out
// MODE 1: LN-folded + gelu -> bf16 out
// MODE 2: plain; xnew = resIn + acc + c0 -> resOut fp32 + outB bf16 + row stats atomics
// MODE 3: plain; xnew = resIn + acc + c0 -> resOut fp32 only
template <int MODE>
__launch_bounds__(256)
__global__ void gemm_bf16(const unsigned short* __restrict__ A, const unsigned short* __restrict__ B,
                          const float* __restrict__ c0, const float* __restrict__ c1,
                          const float* __restrict__ statsIn, const float* __restrict__ resIn,
                          float* __restrict__ resOut, unsigned short* __restrict__ outB,
                          float* __restrict__ statsOut, int M, int Nout, int K) {
    __shared__ unsigned short As[64 * 32];
    __shared__ unsigned short Bs[64 * 32];
    const int m0 = blockIdx.y * 64, n0 = blockIdx.x * 64;
    const int t = threadIdx.x;
    const int wave = t >> 6, lane = t & 63;
    const int wm = (wave & 1) * 32, wn = (wave >> 1) * 32;
    const int srow = t >> 2, scol = (t & 3) * 8;
    const int fr = lane & 15, fq = (lane >> 4) * 8;

    floatx4 acc[2][2] = {};

    const unsigned short* ag = A + (size_t)(m0 + srow) * K + scol;
    const unsigned short* bg = B + (size_t)(n0 + srow) * K + scol;
    unsigned short* as = As + t * 8;
    unsigned short* bs = Bs + t * 8;

    for (int k0 = 0; k0 < K; k0 += 32) {
        __syncthreads();
        gld_lds16(ag + k0, as);
        gld_lds16(bg + k0, bs);
        __syncthreads();
        short8 af[2], bf[2];
#pragma unroll
        for (int i = 0; i < 2; i++)
            af[i] = *(const short8*)&As[(wm + 16 * i + fr) * 32 + fq];
#pragma unroll
        for (int j = 0; j < 2; j++)
            bf[j] = *(const short8*)&Bs[(wn + 16 * j + fr) * 32 + fq];
#pragma unroll
        for (int i = 0; i < 2; i++)
#pragma unroll
            for (int j = 0; j < 2; j++)
                acc[i][j] = __builtin_amdgcn_mfma_f32_16x16x32_bf16(af[i], bf[j], acc[i][j], 0, 0, 0);
    }

    const int er = (lane >> 4) * 4, ec = lane & 15;
    int colj[2]; float c0v[2], c1v[2];
#pragma unroll
    for (int j = 0; j < 2; j++) {
        colj[j] = n0 + wn + 16 * j + ec;
        c0v[j] = c0[colj[j]];
        if (MODE < 2) c1v[j] = c1[colj[j]];
    }

#pragma unroll
    for (int i = 0; i < 2; i++) {
#pragma unroll
        for (int r = 0; r < 4; r++) {
            int row = m0 + wm + 16 * i + er + r;
            if (MODE < 2) {
                float s = statsIn[2 * row], q = statsIn[2 * row + 1];
                float mu = s * (1.0f / DD);
                float var = q * (1.0f / DD) - mu * mu;
                float rm = rsqrtf(var + 1e-5f);
                float rmu = rm * mu;
#pragma unroll
                for (int j = 0; j < 2; j++) {
                    float val = rm * acc[i][j][r] - rmu * c1v[j] + c0v[j];
                    if (MODE == 1) val = 0.5f * val * (1.0f + erff(val * 0.70710678118654752f));
                    outB[(size_t)row * Nout + colj[j]] = f2bf(val);
                }
            } else {
                float xn[2];
#pragma unroll
                for (int j = 0; j < 2; j++) {
                    xn[j] = resIn[(size_t)row * Nout + colj[j]] + acc[i][j][r] + c0v[j];
                    resOut[(size_t)row * Nout + colj[j]] = xn[j];
                    if (MODE == 2) outB[(size_t)row * Nout + colj[j]] = f2bf(xn[j]);
                }
                if (MODE == 2) {
                    float s = xn[0] + xn[1];
                    float q = xn[0] * xn[0] + xn[1] * xn[1];
#pragma unroll
                    for (int off = 1; off < 16; off <<= 1) {
                        s += __shfl_xor(s, off);
                        q += __shfl_xor(q, off);
                    }
                    if ((lane & 15) == 0) {
                        atomicAdd(&statsOut[2 * row], s);
                        atomicAdd(&statsOut[2 * row + 1], q);
                    }
                }
            }
        }
    }
}

// ---------------------------------------------------------------- sparse attention
__global__ void sparse_attn(const unsigned short* __restrict__ qkv, const int* __restrict__ idx,
                            const int* __restrict__ cnt, unsigned short* __restrict__ o) {
    int wave = threadIdx.x >> 6, lane = threadIdx.x & 63;
    int qslot = wave >> 1, half = wave & 1;
    int qi = blockIdx.x * 4 + qslot;
    __shared__ float obuf[4][64][8];
    __shared__ float sbuf[4][64];

    ushort8 qv = *(const ushort8*)(qkv + (size_t)qi * 1536 + lane * 8);
    float qf[8];
#pragma unroll
    for (int e = 0; e < 8; e++) qf[e] = bf2f(qv[e]);

    int c = cnt[qi];
    const int* ir = idx + qi * CAP;
    float sum = 0.f, oa[8] = {};

    for (int j = half; j < c; j += 2) {
        int kj = ir[j];
        const unsigned short* kv_base = qkv + (size_t)kj * 1536;
        ushort8 kv = *(const ushort8*)(kv_base + 512 + lane * 8);
        ushort8 vv = *(const ushort8*)(kv_base + 1024 + lane * 8);
        float d = 0.f;
#pragma unroll
        for (int e = 0; e < 8; e++) d += qf[e] * bf2f(kv[e]);
        d += __shfl_xor(d, 1);
        d += __shfl_xor(d, 2);
        d += __shfl_xor(d, 4);
        d += __shfl_xor(d, 8);
        float p = __expf(d * SCALE);
        sum += p;
#pragma unroll
        for (int e = 0; e < 8; e++) oa[e] += p * bf2f(vv[e]);
    }

    if (half == 1) {
#pragma unroll
        for (int e = 0; e < 8; e++) obuf[qslot][lane][e] = oa[e];
        sbuf[qslot][lane] = sum;
    }
    __syncthreads();
    if (half == 0) {
        sum += sbuf[qslot][lane];
        float inv = 1.0f / sum;
        ushort8 ov;
#pragma unroll
        for (int e = 0; e < 8; e++) ov[e] = f2bf((oa[e] + obuf[qslot][lane][e]) * inv);
        *(ushort8*)(o + (size_t)qi * 512 + lane * 8) = ov;
    }
}

// ---------------------------------------------------------------- launch
extern "C" void kernel_launch(void* const* d_in, const int* in_sizes, int n_in,
                              void* d_out, int out_size, void* d_ws, size_t ws_size,
                              hipStream_t stream) {
    const float* nfeat = (const float*)d_in[0];
    const int*   mask  = (const int*)d_in[1];
    const float* ln1_g = (const float*)d_in[2];
    const float* ln1_b = (const float*)d_in[3];
    const float* wq    = (const float*)d_in[4];
    const float* bq    = (const float*)d_in[5];
    const float* wk    = (const float*)d_in[6];
    const float* bk    = (const float*)d_in[7];
    const float* wv    = (const float*)d_in[8];
    const float* bv    = (const float*)d_in[9];
    const float* wo    = (const float*)d_in[10];
    const float* bo    = (const float*)d_in[11];
    const float* ln2_g = (const float*)d_in[12];
    const float* ln2_b = (const float*)d_in[13];
    const float* fc1_w = (const float*)d_in[14];
    const float* fc1_b = (const float*)d_in[15];
    const float* fc2_w = (const float*)d_in[16];
    const float* fc2_b = (const float*)d_in[17];

    const size_t ND = (size_t)NN * DD;
    float* x            = (float*)d_ws;                    // 8 MB fp32 residual
    unsigned short* xb  = (unsigned short*)(x + ND);       // 4 MB bf16 mirror
    unsigned short* qkv = xb + ND;                         // 12 MB
    unsigned short* o   = qkv + (size_t)NN * 1536;         // 4 MB
    unsigned short* m1  = o + ND;                          // 4 MB
    unsigned short* wc  = m1 + ND;                         // 12 MB folded weights
    float* c0           = (float*)(wc + (size_t)12 * DD * DD);
    float* c1           = c0 + 12 * DD;
    float* S            = c1 + 12 * DD;                    // 4 stats buffers [NN*2]
    int*   idx          = (int*)(S + 4 * NN * 2);
    int*   cnt          = idx + (size_t)NN * CAP;

    FoldArgs fa;
    fa.w[0] = wq; fa.w[1] = wk; fa.w[2] = wv; fa.w[3] = wo; fa.w[4] = fc1_w; fa.w[5] = fc2_w;
    fa.bias[0] = bq; fa.bias[1] = bk; fa.bias[2] = bv; fa.bias[3] = bo; fa.bias[4] = fc1_b; fa.bias[5] = fc2_b;
    fa.ln1_g = ln1_g; fa.ln1_b = ln1_b; fa.ln2_g = ln2_g; fa.ln2_b = ln2_b;

    fold_weights<<<dim3(128, 12), 256, 0, stream>>>(fa, wc, c0, c1);
    build_idx_kernel<<<NN, 256, 0, stream>>>(mask, idx, cnt);
    init_stats<<<NN / 4, 256, 0, stream>>>(nfeat, xb, S);                 // S0
    zero_kernel<<<24, 1024, 0, stream>>>(S + NN * 2, 3 * NN * 2);         // S1..S3

    for (int l = 0; l < 2; l++) {
        unsigned short* wl = wc + (size_t)l * 6 * DD * DD;
        float* cl0 = c0 + l * 6 * DD;
        float* cl1 = c1 + l * 6 * DD;
        float* Sa = S + (size_t)(2 * l) * NN * 2;       // ln1 stats
        float* Sb = S + (size_t)(2 * l + 1) * NN * 2;   // ln2 stats
        const float* resIn0 = (l == 0) ? nfeat : x;

        // QKV (LN1-folded)
        gemm_bf16<0><<<dim3(24, 64), 256, 0, stream>>>(xb, wl, cl0, cl1, Sa,
                                                       nullptr, nullptr, qkv, nullptr, NN, 1536, DD);
        sparse_attn<<<NN / 4, 512, 0, stream>>>(qkv, idx, cnt, o);
        // O-proj + residual + ln2 stats
        gemm_bf16<2><<<dim3(8, 64), 256, 0, stream>>>(o, wl + (size_t)3 * DD * DD, cl0 + 3 * DD, nullptr,
                                                      nullptr, resIn0, x, xb, Sb, NN, DD, DD);
        // fc1 (LN2-folded, gelu)
        gemm_bf16<1><<<dim3(8, 64), 256, 0, stream>>>(xb, wl + (size_t)4 * DD * DD, cl0 + 4 * DD, cl1 + 4 * DD, Sb,
                                                      nullptr, nullptr, m1, nullptr, NN, FF, DD);
        // fc2 + residual (+ next layer's ln1 stats, or final out)
        if (l == 0) {
            gemm_bf16<2><<<dim3(8, 64), 256, 0, stream>>>(m1, wl + (size_t)5 * DD * DD, cl0 + 5 * DD, nullptr,
                                                          nullptr, x, x, xb, S + (size_t)2 * NN * 2, NN, DD, FF);
        } else {
            gemm_bf16<3><<<dim3(8, 64), 256, 0, stream>>>(m1, wl + (size_t)5 * DD * DD, cl0 + 5 * DD, nullptr,
                                                          nullptr, x, (float*)d_out, nullptr, nullptr, NN, DD, FF);
        }
    }
}